// Round 4
// baseline (331.256 us; speedup 1.0000x reference)
//
#include <hip/hip_runtime.h>
#include <hip/hip_bf16.h>
#include <hip/hip_cooperative_groups.h>
#include <math.h>

namespace cg = cooperative_groups;

#define N 4096

// ============================ fused cooperative kernel ============================
// 256 blocks x 256 threads, 1 block/CU, all co-resident. Phases separated by
// grid-wide sync (+ __threadfence for cross-XCD visibility of plain stores).
__global__ void k_fused(const float* __restrict__ preds, const float* __restrict__ target,
                        float* __restrict__ y, float* __restrict__ s, int* __restrict__ perm,
                        float* __restrict__ P, float* __restrict__ r, float* __restrict__ out)
{
    cg::grid_group grid = cg::this_grid();
    __shared__ __align__(16) float sp[N];
    __shared__ __align__(16) float st[N];
    __shared__ int part[16][17];
    __shared__ float fpart[16][17];
    __shared__ int rks[16];
    __shared__ __align__(16) float mArr[4][256];
    __shared__ float incl[4][257];
    __shared__ double cj[16];
    __shared__ double wsum[4];
    __shared__ double red[4];

    const int tid = threadIdx.x;
    const int b = blockIdx.x;
    const int lane = tid & 63, wid = tid >> 6;

    // ---------------- Phase A: rank(preds) fused with softmax matvec -> y ----------
    for (int m = 0; m < 16; m++) {
        int idx = tid + 256 * m;
        sp[idx] = preds[idx];
        st[idx] = target[idx];
    }
    __syncthreads();
    {
        int eloc = tid & 15, slice = tid >> 4;
        int i0 = b * 16 + eloc;
        float v = sp[i0];
        int cnt = 0;
        const float4* sp4 = (const float4*)sp;
        for (int it = 0; it < 64; it++) {
            int q = slice * 64 + ((it + slice) & 63); // stagger across banks
            float4 a = sp4[q];
            int j = q * 4;
            cnt += (a.x < v) || (a.x == v && (j + 0) < i0);
            cnt += (a.y < v) || (a.y == v && (j + 1) < i0);
            cnt += (a.z < v) || (a.z == v && (j + 2) < i0);
            cnt += (a.w < v) || (a.w == v && (j + 3) < i0);
        }
        part[eloc][slice] = cnt;
        __syncthreads();
        if (tid < 16) {
            int rr = 0;
            #pragma unroll
            for (int q = 0; q < 16; q++) rr += part[tid][q];
            rks[tid] = rr;
        }
        __syncthreads();
        // one softmax row per wave (row max is exactly 0 — diagonal term)
        #pragma unroll
        for (int t = 0; t < 4; t++) {
            int rr = 4 * t + wid;           // owned element index 0..15
            float xv = sp[b * 16 + rr];
            float Z = 0.f, Nm = 0.f;
            #pragma unroll 4
            for (int m = 0; m < 64; m++) {
                int j = lane + 64 * m;
                float dx = xv - sp[j];
                float e = __expf(-100.0f * dx * dx);
                Z += e;
                Nm += e * st[j];
            }
            #pragma unroll
            for (int d = 32; d; d >>= 1) {
                Z += __shfl_down(Z, d);
                Nm += __shfl_down(Nm, d);
            }
            if (lane == 0) y[rks[rr]] = Nm / Z;
        }
    }
    __threadfence();
    grid.sync();

    // ---------------- Phase B: descending stable rank of y -> s, perm --------------
    for (int m = 0; m < 16; m++) sp[tid + 256 * m] = y[tid + 256 * m];
    __syncthreads();
    {
        int eloc = tid & 15, slice = tid >> 4;
        int i0 = b * 16 + eloc;
        float v = sp[i0];
        int cnt = 0;
        const float4* sp4 = (const float4*)sp;
        for (int it = 0; it < 64; it++) {
            int q = slice * 64 + ((it + slice) & 63);
            float4 a = sp4[q];
            int j = q * 4;
            cnt += (a.x > v) || (a.x == v && (j + 0) < i0);
            cnt += (a.y > v) || (a.y == v && (j + 1) < i0);
            cnt += (a.z > v) || (a.z == v && (j + 2) < i0);
            cnt += (a.w > v) || (a.w == v && (j + 3) < i0);
        }
        part[eloc][slice] = cnt;
        __syncthreads();
        if (tid < 16) {
            int rr = 0;
            #pragma unroll
            for (int q = 0; q < 16; q++) rr += part[tid][q];
            int i2 = b * 16 + tid;
            s[rr] = sp[i2] * 100.0f;
            perm[rr] = i2;
        }
    }
    __threadfence();
    grid.sync();

    // ---------------- Phase C: fused f64 cumsum + isotonic min-max -> P[b][:] ------
    {
        const int j0 = b * 16;
        const int kbase = tid * 16;
        double loc[16];
        {
            const float4* s4 = (const float4*)s;
            double tot = 0.0;
            #pragma unroll
            for (int q = 0; q < 4; q++) {
                float4 a = s4[tid * 4 + q];
                int t0 = kbase + q * 4;
                tot += (double)(N - (t0 + 0)) - (double)a.x; loc[q * 4 + 0] = tot;
                tot += (double)(N - (t0 + 1)) - (double)a.y; loc[q * 4 + 1] = tot;
                tot += (double)(N - (t0 + 2)) - (double)a.z; loc[q * 4 + 2] = tot;
                tot += (double)(N - (t0 + 3)) - (double)a.w; loc[q * 4 + 3] = tot;
            }
            double w = tot;
            #pragma unroll
            for (int d = 1; d < 64; d <<= 1) {
                double o = __shfl_up(w, d);
                if (lane >= d) w += o;
            }
            if (lane == 63) wsum[wid] = w;
            __syncthreads();
            double base = 0.0;
            #pragma unroll
            for (int q = 0; q < 4; q++) if (q < wid) base += wsum[q];
            double excl = base + (w - tot);
            #pragma unroll
            for (int e = 0; e < 16; e++) loc[e] += excl; // loc[e] = cs[kbase+1+e]
            if (tid == b) {
                cj[0] = excl;
                #pragma unroll
                for (int m = 1; m < 16; m++) cj[m] = loc[m - 1];
            }
        }
        __syncthreads();

        float vloc[16];
        #pragma unroll
        for (int e = 0; e < 16; e++) vloc[e] = -INFINITY;
        float ls[4][16];
        for (int grp = 0; grp < 4; grp++) {
            #pragma unroll
            for (int rq = 0; rq < 4; rq++) {
                int j = j0 + grp * 4 + rq;
                double csj = cj[grp * 4 + rq];
                float run = INFINITY;
                #pragma unroll
                for (int e = 15; e >= 0; e--) {
                    int k = kbase + e;
                    float f = INFINITY;
                    if (k >= j) f = (float)(loc[e] - csj) * __builtin_amdgcn_rcpf((float)(k - j + 1));
                    run = fminf(f, run);
                    ls[rq][e] = run;
                }
                mArr[rq][tid] = run;
            }
            __syncthreads();
            {
                int w = tid >> 6, l = tid & 63;
                float4 xv = ((const float4*)mArr[w])[l];
                float s3 = xv.w;
                float s2 = fminf(xv.z, s3);
                float s1 = fminf(xv.y, s2);
                float s0 = fminf(xv.x, s1);
                float t = s0;
                #pragma unroll
                for (int d = 1; d < 64; d <<= 1) {
                    float o = __shfl_down(t, d);
                    if (l + d < 64) t = fminf(t, o);
                }
                float after = __shfl_down(t, 1);
                if (l == 63) after = INFINITY;
                incl[w][4 * l + 0] = fminf(s0, after);
                incl[w][4 * l + 1] = fminf(s1, after);
                incl[w][4 * l + 2] = fminf(s2, after);
                incl[w][4 * l + 3] = fminf(s3, after);
                if (l == 0) incl[w][256] = INFINITY;
            }
            __syncthreads();
            #pragma unroll
            for (int rq = 0; rq < 4; rq++) {
                int j = j0 + grp * 4 + rq;
                float aft = incl[rq][tid + 1];
                #pragma unroll
                for (int e = 0; e < 16; e++) {
                    int i = kbase + e;
                    float sv = fminf(ls[rq][e], aft);
                    if (i >= j) vloc[e] = fmaxf(vloc[e], sv);
                }
            }
            __syncthreads();
        }
        float4* P4 = (float4*)(P + (size_t)b * N);
        #pragma unroll
        for (int q = 0; q < 4; q++)
            P4[tid * 4 + q] = make_float4(vloc[4 * q + 0], vloc[4 * q + 1],
                                          vloc[4 * q + 2], vloc[4 * q + 3]);
    }
    __threadfence();
    grid.sync();

    // ---------------- Phase D: T[i] = max_b P[b][i]; scatter r ---------------------
    {
        int col = tid & 15, slice = tid >> 4;
        int i = b * 16 + col;
        float m = -INFINITY;
        #pragma unroll
        for (int q = 0; q < 16; q++) {
            int bb = slice * 16 + q;
            m = fmaxf(m, P[(size_t)bb * N + i]);
        }
        fpart[col][slice] = m;
        __syncthreads();
        if (tid < 16) {
            float T = -INFINITY;
            #pragma unroll
            for (int q = 0; q < 16; q++) T = fmaxf(T, fpart[tid][q]);
            int i2 = b * 16 + tid;
            r[perm[i2]] = s[i2] + T;
        }
    }
    __threadfence();
    grid.sync();

    // ---------------- Phase E: diff-sum over r, emit out (block 0 only) ------------
    if (b == 0) {
        const float4* r4 = (const float4*)r;
        float a[16];
        #pragma unroll
        for (int q = 0; q < 4; q++) {
            float4 x = r4[tid * 4 + q];
            a[q * 4 + 0] = x.x; a[q * 4 + 1] = x.y; a[q * 4 + 2] = x.z; a[q * 4 + 3] = x.w;
        }
        float extra = (tid < 255) ? r[tid * 16 + 16] : 0.0f;
        double acc = 0.0;
        #pragma unroll
        for (int e = 0; e < 16; e++) {
            int d = tid * 16 + e;
            float nxt = (e < 15) ? a[e + 1] : extra;
            if (d < N - 1) acc += fabs((double)nxt - (double)a[e]);
        }
        #pragma unroll
        for (int dd = 32; dd; dd >>= 1) acc += __shfl_down(acc, dd);
        if (lane == 0) red[wid] = acc;
        __syncthreads();
        if (tid == 0) {
            double ds = red[0] + red[1] + red[2] + red[3];
            double xi = 1.0 - 3.0 * ds / ((double)N * (double)N - 1.0);
            out[0] = (float)(-1.0 * xi); // loss = -WEIGHT * xi
            out[1] = (float)xi;
        }
    }
}

// ============================ fallback path (round-3 proven) ======================
__global__ void k_rank_preds(const float* __restrict__ preds, float* __restrict__ xs) {
    __shared__ __align__(16) float sp[N];
    __shared__ int part[16][17];
    int tid = threadIdx.x;
    int b = blockIdx.x;
    for (int m = 0; m < 16; m++) sp[tid + 256 * m] = preds[tid + 256 * m];
    __syncthreads();
    int eloc = tid & 15;
    int slice = tid >> 4;
    int i = b * 16 + eloc;
    float v = sp[i];
    int cnt = 0;
    const float4* sp4 = (const float4*)sp;
    for (int it = 0; it < 64; it++) {
        int q = slice * 64 + ((it + slice) & 63);
        float4 a = sp4[q];
        int j = q * 4;
        cnt += (a.x < v) || (a.x == v && (j + 0) < i);
        cnt += (a.y < v) || (a.y == v && (j + 1) < i);
        cnt += (a.z < v) || (a.z == v && (j + 2) < i);
        cnt += (a.w < v) || (a.w == v && (j + 3) < i);
    }
    part[eloc][slice] = cnt;
    __syncthreads();
    if (tid < 16) {
        int r = 0;
        #pragma unroll
        for (int s = 0; s < 16; s++) r += part[tid][s];
        xs[r] = sp[b * 16 + tid];
    }
}

__global__ void k_softmax_mv(const float* __restrict__ preds, const float* __restrict__ target,
                             const float* __restrict__ xs, float* __restrict__ y) {
    __shared__ float sp[N];
    __shared__ float st[N];
    __shared__ float rz[4], rn[4];
    int tid = threadIdx.x;
    for (int m = 0; m < 16; m++) {
        int idx = tid + 256 * m;
        sp[idx] = preds[idx];
        st[idx] = target[idx];
    }
    __syncthreads();
    int row0 = blockIdx.x * 8;
    for (int rr = 0; rr < 8; rr++) {
        int i = row0 + rr;
        float xv = xs[i];
        float Z = 0.f, Nm = 0.f;
        #pragma unroll 4
        for (int m = 0; m < 16; m++) {
            int jj = tid + 256 * m;
            float dx = xv - sp[jj];
            float e = __expf(-100.0f * dx * dx);
            Z += e;
            Nm += e * st[jj];
        }
        #pragma unroll
        for (int d = 32; d; d >>= 1) {
            Z += __shfl_down(Z, d);
            Nm += __shfl_down(Nm, d);
        }
        if ((tid & 63) == 0) { rz[tid >> 6] = Z; rn[tid >> 6] = Nm; }
        __syncthreads();
        if (tid == 0) {
            float Zt = rz[0] + rz[1] + rz[2] + rz[3];
            float Nt = rn[0] + rn[1] + rn[2] + rn[3];
            y[i] = Nt / Zt;
        }
        __syncthreads();
    }
}

__global__ void k_rank_y(const float* __restrict__ y, float* __restrict__ s_out,
                         int* __restrict__ perm_out) {
    __shared__ __align__(16) float sy[N];
    __shared__ int part[16][17];
    int tid = threadIdx.x;
    int b = blockIdx.x;
    for (int m = 0; m < 16; m++) sy[tid + 256 * m] = y[tid + 256 * m];
    __syncthreads();
    int eloc = tid & 15;
    int slice = tid >> 4;
    int i = b * 16 + eloc;
    float v = sy[i];
    int cnt = 0;
    const float4* sy4 = (const float4*)sy;
    for (int it = 0; it < 64; it++) {
        int q = slice * 64 + ((it + slice) & 63);
        float4 a = sy4[q];
        int j = q * 4;
        cnt += (a.x > v) || (a.x == v && (j + 0) < i);
        cnt += (a.y > v) || (a.y == v && (j + 1) < i);
        cnt += (a.z > v) || (a.z == v && (j + 2) < i);
        cnt += (a.w > v) || (a.w == v && (j + 3) < i);
    }
    part[eloc][slice] = cnt;
    __syncthreads();
    if (tid < 16) {
        int r = 0;
        #pragma unroll
        for (int s = 0; s < 16; s++) r += part[tid][s];
        int i2 = b * 16 + tid;
        s_out[r] = sy[i2] * 100.0f;
        perm_out[r] = i2;
    }
}

__global__ void k_iso3(const float* __restrict__ s, float* __restrict__ P) {
    __shared__ __align__(16) float mArr[4][256];
    __shared__ float incl[4][257];
    __shared__ double cj[16];
    __shared__ double wsum[4];
    int tid = threadIdx.x;
    int b = blockIdx.x;
    int j0 = b * 16;
    int kbase = tid * 16;
    int lane = tid & 63, wid = tid >> 6;
    double loc[16];
    {
        const float4* s4 = (const float4*)s;
        double tot = 0.0;
        #pragma unroll
        for (int q = 0; q < 4; q++) {
            float4 a = s4[tid * 4 + q];
            int t0 = kbase + q * 4;
            tot += (double)(N - (t0 + 0)) - (double)a.x; loc[q * 4 + 0] = tot;
            tot += (double)(N - (t0 + 1)) - (double)a.y; loc[q * 4 + 1] = tot;
            tot += (double)(N - (t0 + 2)) - (double)a.z; loc[q * 4 + 2] = tot;
            tot += (double)(N - (t0 + 3)) - (double)a.w; loc[q * 4 + 3] = tot;
        }
        double w = tot;
        #pragma unroll
        for (int d = 1; d < 64; d <<= 1) {
            double o = __shfl_up(w, d);
            if (lane >= d) w += o;
        }
        if (lane == 63) wsum[wid] = w;
        __syncthreads();
        double base = 0.0;
        #pragma unroll
        for (int q = 0; q < 4; q++) if (q < wid) base += wsum[q];
        double excl = base + (w - tot);
        #pragma unroll
        for (int e = 0; e < 16; e++) loc[e] += excl;
        if (tid == b) {
            cj[0] = excl;
            #pragma unroll
            for (int m = 1; m < 16; m++) cj[m] = loc[m - 1];
        }
    }
    __syncthreads();
    float vloc[16];
    #pragma unroll
    for (int e = 0; e < 16; e++) vloc[e] = -INFINITY;
    float ls[4][16];
    for (int grp = 0; grp < 4; grp++) {
        #pragma unroll
        for (int rq = 0; rq < 4; rq++) {
            int j = j0 + grp * 4 + rq;
            double csj = cj[grp * 4 + rq];
            float run = INFINITY;
            #pragma unroll
            for (int e = 15; e >= 0; e--) {
                int k = kbase + e;
                float f = INFINITY;
                if (k >= j) f = (float)(loc[e] - csj) * __builtin_amdgcn_rcpf((float)(k - j + 1));
                run = fminf(f, run);
                ls[rq][e] = run;
            }
            mArr[rq][tid] = run;
        }
        __syncthreads();
        {
            int w = tid >> 6, l = tid & 63;
            float4 xv = ((const float4*)mArr[w])[l];
            float s3 = xv.w;
            float s2 = fminf(xv.z, s3);
            float s1 = fminf(xv.y, s2);
            float s0 = fminf(xv.x, s1);
            float t = s0;
            #pragma unroll
            for (int d = 1; d < 64; d <<= 1) {
                float o = __shfl_down(t, d);
                if (l + d < 64) t = fminf(t, o);
            }
            float after = __shfl_down(t, 1);
            if (l == 63) after = INFINITY;
            incl[w][4 * l + 0] = fminf(s0, after);
            incl[w][4 * l + 1] = fminf(s1, after);
            incl[w][4 * l + 2] = fminf(s2, after);
            incl[w][4 * l + 3] = fminf(s3, after);
            if (l == 0) incl[w][256] = INFINITY;
        }
        __syncthreads();
        #pragma unroll
        for (int rq = 0; rq < 4; rq++) {
            int j = j0 + grp * 4 + rq;
            float aft = incl[rq][tid + 1];
            #pragma unroll
            for (int e = 0; e < 16; e++) {
                int i = kbase + e;
                float sv = fminf(ls[rq][e], aft);
                if (i >= j) vloc[e] = fmaxf(vloc[e], sv);
            }
        }
        __syncthreads();
    }
    float4* P4 = (float4*)(P + (size_t)b * N);
    #pragma unroll
    for (int q = 0; q < 4; q++)
        P4[tid * 4 + q] = make_float4(vloc[4 * q + 0], vloc[4 * q + 1],
                                      vloc[4 * q + 2], vloc[4 * q + 3]);
}

__global__ void k_reduce(const float* __restrict__ P, const float* __restrict__ s,
                         const int* __restrict__ perm, float* __restrict__ r) {
    __shared__ float part[16][17];
    int tid = threadIdx.x;
    int col = tid & 15;
    int slice = tid >> 4;
    int i = blockIdx.x * 16 + col;
    float m = -INFINITY;
    #pragma unroll
    for (int q = 0; q < 16; q++) {
        int b = slice * 16 + q;
        m = fmaxf(m, P[(size_t)b * N + i]);
    }
    part[col][slice] = m;
    __syncthreads();
    if (tid < 16) {
        float T = -INFINITY;
        #pragma unroll
        for (int q = 0; q < 16; q++) T = fmaxf(T, part[tid][q]);
        int i2 = blockIdx.x * 16 + tid;
        r[perm[i2]] = s[i2] + T;
    }
}

__global__ void k_finish2(const float* __restrict__ r, float* __restrict__ out) {
    __shared__ double red[4];
    int tid = threadIdx.x;
    const float4* r4 = (const float4*)r;
    float a[16];
    #pragma unroll
    for (int q = 0; q < 4; q++) {
        float4 x = r4[tid * 4 + q];
        a[q * 4 + 0] = x.x; a[q * 4 + 1] = x.y; a[q * 4 + 2] = x.z; a[q * 4 + 3] = x.w;
    }
    float extra = (tid < 255) ? r[tid * 16 + 16] : 0.0f;
    double acc = 0.0;
    #pragma unroll
    for (int e = 0; e < 16; e++) {
        int d = tid * 16 + e;
        float nxt = (e < 15) ? a[e + 1] : extra;
        if (d < N - 1) acc += fabs((double)nxt - (double)a[e]);
    }
    #pragma unroll
    for (int dd = 32; dd; dd >>= 1) acc += __shfl_down(acc, dd);
    if ((tid & 63) == 0) red[tid >> 6] = acc;
    __syncthreads();
    if (tid == 0) {
        double ds = red[0] + red[1] + red[2] + red[3];
        double xi = 1.0 - 3.0 * ds / ((double)N * (double)N - 1.0);
        out[0] = (float)(-1.0 * xi);
        out[1] = (float)xi;
    }
}

extern "C" void kernel_launch(void* const* d_in, const int* in_sizes, int n_in,
                              void* d_out, int out_size, void* d_ws, size_t ws_size,
                              hipStream_t stream) {
    const float* preds  = (const float*)d_in[0];
    const float* target = (const float*)d_in[1];
    float* out = (float*)d_out;

    char* ws = (char*)d_ws;
    float* xs   = (float*)(ws);            // 16 KB (fallback only)
    float* y    = (float*)(ws + 16384);    // 16 KB
    float* s    = (float*)(ws + 32768);    // 16 KB
    int*   perm = (int*)(ws + 49152);      // 16 KB
    float* r    = (float*)(ws + 65536);    // 16 KB
    float* P    = (float*)(ws + 81920);    // 4 MB

    void* args[] = { (void*)&preds, (void*)&target, (void*)&y, (void*)&s,
                     (void*)&perm, (void*)&P, (void*)&r, (void*)&out };
    hipError_t err = hipLaunchCooperativeKernel((void*)k_fused, dim3(256), dim3(256),
                                                args, 0, stream);
    if (err != hipSuccess) {
        // fallback: round-3 proven multi-kernel path
        k_rank_preds<<<256, 256, 0, stream>>>(preds, xs);
        k_softmax_mv<<<512, 256, 0, stream>>>(preds, target, xs, y);
        k_rank_y<<<256, 256, 0, stream>>>(y, s, perm);
        k_iso3<<<256, 256, 0, stream>>>(s, P);
        k_reduce<<<256, 256, 0, stream>>>(P, s, perm, r);
        k_finish2<<<1, 256, 0, stream>>>(r, out);
    }
}

// Round 5
// 137.756 us; speedup vs baseline: 2.4047x; 2.4047x over previous
//
#include <hip/hip_runtime.h>
#include <hip/hip_bf16.h>
#include <math.h>

#define N 4096

// K_A: fused ascending rank of preds + softmax matvec -> y.  256 blocks x 256.
// Block b owns preds[16b..16b+16); computes each one's global rank by counting,
// then evaluates that softmax row (one row per wave): y[rank] = sm(row).target.
// Row max of the logits is exactly 0 (diagonal term), so single-pass exp is
// numerically identical to jax's subtract-max softmax.
// Block 0 also zeroes the ticket counter consumed by k_D.
__global__ void k_A(const float* __restrict__ preds, const float* __restrict__ target,
                    float* __restrict__ y, int* __restrict__ counter) {
    __shared__ __align__(16) float sp[N];
    __shared__ __align__(16) float st[N];
    __shared__ int part[16][17];
    __shared__ int rks[16];
    int tid = threadIdx.x;
    int b = blockIdx.x;
    int lane = tid & 63, wid = tid >> 6;
    if (b == 0 && tid == 0) *counter = 0;
    for (int m = 0; m < 16; m++) {
        int idx = tid + 256 * m;
        sp[idx] = preds[idx];
        st[idx] = target[idx];
    }
    __syncthreads();
    {
        int eloc = tid & 15, slice = tid >> 4;
        int i0 = b * 16 + eloc;
        float v = sp[i0];
        int cnt = 0;
        const float4* sp4 = (const float4*)sp;
        for (int it = 0; it < 64; it++) {
            int q = slice * 64 + ((it + slice) & 63); // stagger across banks
            float4 a = sp4[q];
            int j = q * 4;
            cnt += (a.x < v) || (a.x == v && (j + 0) < i0);
            cnt += (a.y < v) || (a.y == v && (j + 1) < i0);
            cnt += (a.z < v) || (a.z == v && (j + 2) < i0);
            cnt += (a.w < v) || (a.w == v && (j + 3) < i0);
        }
        part[eloc][slice] = cnt;
    }
    __syncthreads();
    if (tid < 16) {
        int rr = 0;
        #pragma unroll
        for (int q = 0; q < 16; q++) rr += part[tid][q];
        rks[tid] = rr;
    }
    __syncthreads();
    #pragma unroll
    for (int t = 0; t < 4; t++) {
        int rr = 4 * t + wid;               // owned element 0..15
        float xv = sp[b * 16 + rr];
        float Z = 0.f, Nm = 0.f;
        #pragma unroll 4
        for (int m = 0; m < 64; m++) {
            int j = lane + 64 * m;
            float dx = xv - sp[j];
            float e = __expf(-100.0f * dx * dx);
            Z += e;
            Nm += e * st[j];
        }
        #pragma unroll
        for (int d = 32; d; d >>= 1) {
            Z += __shfl_down(Z, d);
            Nm += __shfl_down(Nm, d);
        }
        if (lane == 0) y[rks[rr]] = Nm / Z;
    }
}

// K_B: descending stable rank of y; s[r] = y*100, perm[r] = i.  256 blocks x 256.
__global__ void k_B(const float* __restrict__ y, float* __restrict__ s_out,
                    int* __restrict__ perm_out) {
    __shared__ __align__(16) float sy[N];
    __shared__ int part[16][17];
    int tid = threadIdx.x;
    int b = blockIdx.x;
    for (int m = 0; m < 16; m++) sy[tid + 256 * m] = y[tid + 256 * m];
    __syncthreads();
    int eloc = tid & 15;
    int slice = tid >> 4;
    int i = b * 16 + eloc;
    float v = sy[i];
    int cnt = 0;
    const float4* sy4 = (const float4*)sy;
    for (int it = 0; it < 64; it++) {
        int q = slice * 64 + ((it + slice) & 63);
        float4 a = sy4[q];
        int j = q * 4;
        cnt += (a.x > v) || (a.x == v && (j + 0) < i);
        cnt += (a.y > v) || (a.y == v && (j + 1) < i);
        cnt += (a.z > v) || (a.z == v && (j + 2) < i);
        cnt += (a.w > v) || (a.w == v && (j + 3) < i);
    }
    part[eloc][slice] = cnt;
    __syncthreads();
    if (tid < 16) {
        int r = 0;
        #pragma unroll
        for (int q = 0; q < 16; q++) r += part[tid][q];
        int i2 = b * 16 + tid;
        s_out[r] = sy[i2] * 100.0f;
        perm_out[r] = i2;
    }
}

// K_C: fused f64 cumsum of z[t]=(N-t)-s[t] + isotonic min-max scan.
// Block b covers rows j in [16b,16b+16); writes per-block column-max P[b][:].
__global__ void k_C(const float* __restrict__ s, float* __restrict__ P) {
    __shared__ __align__(16) float mArr[4][256];
    __shared__ float incl[4][257];
    __shared__ double cj[16];
    __shared__ double wsum[4];
    int tid = threadIdx.x;
    int b = blockIdx.x;
    int j0 = b * 16;
    int kbase = tid * 16;
    int lane = tid & 63, wid = tid >> 6;
    double loc[16];
    {
        const float4* s4 = (const float4*)s;
        double tot = 0.0;
        #pragma unroll
        for (int q = 0; q < 4; q++) {
            float4 a = s4[tid * 4 + q];
            int t0 = kbase + q * 4;
            tot += (double)(N - (t0 + 0)) - (double)a.x; loc[q * 4 + 0] = tot;
            tot += (double)(N - (t0 + 1)) - (double)a.y; loc[q * 4 + 1] = tot;
            tot += (double)(N - (t0 + 2)) - (double)a.z; loc[q * 4 + 2] = tot;
            tot += (double)(N - (t0 + 3)) - (double)a.w; loc[q * 4 + 3] = tot;
        }
        double w = tot;
        #pragma unroll
        for (int d = 1; d < 64; d <<= 1) {
            double o = __shfl_up(w, d);
            if (lane >= d) w += o;
        }
        if (lane == 63) wsum[wid] = w;
        __syncthreads();
        double base = 0.0;
        #pragma unroll
        for (int q = 0; q < 4; q++) if (q < wid) base += wsum[q];
        double excl = base + (w - tot);
        #pragma unroll
        for (int e = 0; e < 16; e++) loc[e] += excl; // loc[e] = cs[kbase+1+e]
        if (tid == b) {                              // owns cs[j0..j0+16)
            cj[0] = excl;
            #pragma unroll
            for (int m = 1; m < 16; m++) cj[m] = loc[m - 1];
        }
    }
    __syncthreads();
    float vloc[16];
    #pragma unroll
    for (int e = 0; e < 16; e++) vloc[e] = -INFINITY;
    float ls[4][16];
    for (int grp = 0; grp < 4; grp++) {
        #pragma unroll
        for (int rq = 0; rq < 4; rq++) {
            int j = j0 + grp * 4 + rq;
            double csj = cj[grp * 4 + rq];
            float run = INFINITY;
            #pragma unroll
            for (int e = 15; e >= 0; e--) {
                int k = kbase + e;
                float f = INFINITY;
                if (k >= j) f = (float)(loc[e] - csj) * __builtin_amdgcn_rcpf((float)(k - j + 1));
                run = fminf(f, run);
                ls[rq][e] = run;
            }
            mArr[rq][tid] = run;
        }
        __syncthreads();
        {
            int w = tid >> 6, l = tid & 63;
            float4 xv = ((const float4*)mArr[w])[l];
            float s3 = xv.w;
            float s2 = fminf(xv.z, s3);
            float s1 = fminf(xv.y, s2);
            float s0 = fminf(xv.x, s1);
            float t = s0;
            #pragma unroll
            for (int d = 1; d < 64; d <<= 1) {
                float o = __shfl_down(t, d);
                if (l + d < 64) t = fminf(t, o);
            }
            float after = __shfl_down(t, 1);
            if (l == 63) after = INFINITY;
            incl[w][4 * l + 0] = fminf(s0, after);
            incl[w][4 * l + 1] = fminf(s1, after);
            incl[w][4 * l + 2] = fminf(s2, after);
            incl[w][4 * l + 3] = fminf(s3, after);
            if (l == 0) incl[w][256] = INFINITY;
        }
        __syncthreads();
        #pragma unroll
        for (int rq = 0; rq < 4; rq++) {
            int j = j0 + grp * 4 + rq;
            float aft = incl[rq][tid + 1];
            #pragma unroll
            for (int e = 0; e < 16; e++) {
                int i = kbase + e;
                float sv = fminf(ls[rq][e], aft);
                if (i >= j) vloc[e] = fmaxf(vloc[e], sv);
            }
        }
        __syncthreads();
    }
    float4* P4 = (float4*)(P + (size_t)b * N);
    #pragma unroll
    for (int q = 0; q < 4; q++)
        P4[tid * 4 + q] = make_float4(vloc[4 * q + 0], vloc[4 * q + 1],
                                      vloc[4 * q + 2], vloc[4 * q + 3]);
}

// K_D: T[i] = max_b P[b][i]; r[perm[i]] = s[i] + T[i]; then opportunistic
// last-block (device-scope ticket) computes the diff-sum and writes out.
__global__ void k_D(const float* __restrict__ P, const float* __restrict__ s,
                    const int* __restrict__ perm, float* __restrict__ r,
                    int* __restrict__ counter, float* __restrict__ out) {
    __shared__ float part[16][17];
    __shared__ double red[4];
    __shared__ int sticket;
    int tid = threadIdx.x;
    int col = tid & 15;
    int slice = tid >> 4;
    int i = blockIdx.x * 16 + col;
    float m = -INFINITY;
    #pragma unroll
    for (int q = 0; q < 16; q++) {
        int b = slice * 16 + q;
        m = fmaxf(m, P[(size_t)b * N + i]);
    }
    part[col][slice] = m;
    __syncthreads();
    if (tid < 16) {
        float T = -INFINITY;
        #pragma unroll
        for (int q = 0; q < 16; q++) T = fmaxf(T, part[tid][q]);
        int i2 = blockIdx.x * 16 + tid;
        r[perm[i2]] = s[i2] + T;
    }
    __threadfence();                 // release r stores device-wide
    __syncthreads();
    if (tid == 0) sticket = atomicAdd(counter, 1);
    __syncthreads();
    if (sticket != 255) return;      // not the last block to finish
    __threadfence();                 // acquire: all other blocks' r visible
    const float4* r4 = (const float4*)r;
    float a[16];
    #pragma unroll
    for (int q = 0; q < 4; q++) {
        float4 x = r4[tid * 4 + q];
        a[q * 4 + 0] = x.x; a[q * 4 + 1] = x.y; a[q * 4 + 2] = x.z; a[q * 4 + 3] = x.w;
    }
    float extra = (tid < 255) ? r[tid * 16 + 16] : 0.0f;
    double acc = 0.0;
    #pragma unroll
    for (int e = 0; e < 16; e++) {
        int d = tid * 16 + e;
        float nxt = (e < 15) ? a[e + 1] : extra;
        if (d < N - 1) acc += fabs((double)nxt - (double)a[e]);
    }
    #pragma unroll
    for (int dd = 32; dd; dd >>= 1) acc += __shfl_down(acc, dd);
    if ((tid & 63) == 0) red[tid >> 6] = acc;
    __syncthreads();
    if (tid == 0) {
        double ds = red[0] + red[1] + red[2] + red[3];
        double xi = 1.0 - 3.0 * ds / ((double)N * (double)N - 1.0);
        out[0] = (float)(-1.0 * xi);  // loss = -WEIGHT * xi
        out[1] = (float)xi;
    }
}

extern "C" void kernel_launch(void* const* d_in, const int* in_sizes, int n_in,
                              void* d_out, int out_size, void* d_ws, size_t ws_size,
                              hipStream_t stream) {
    const float* preds  = (const float*)d_in[0];
    const float* target = (const float*)d_in[1];
    float* out = (float*)d_out;

    char* ws = (char*)d_ws;
    float* y       = (float*)(ws);            // 16 KB
    float* s       = (float*)(ws + 16384);    // 16 KB
    int*   perm    = (int*)(ws + 32768);      // 16 KB
    float* r       = (float*)(ws + 49152);    // 16 KB
    int*   counter = (int*)(ws + 65536);      // 4 B
    float* P       = (float*)(ws + 81920);    // 4 MB

    k_A<<<256, 256, 0, stream>>>(preds, target, y, counter);
    k_B<<<256, 256, 0, stream>>>(y, s, perm);
    k_C<<<256, 256, 0, stream>>>(s, P);
    k_D<<<256, 256, 0, stream>>>(P, s, perm, r, counter, out);
}

// Round 6
// 123.263 us; speedup vs baseline: 2.6874x; 1.1176x over previous
//
#include <hip/hip_runtime.h>
#include <hip/hip_bf16.h>
#include <math.h>

#define N 4096

// K_A: fused ascending rank of preds + softmax matvec -> y.  256 blocks x 256.
// Block b owns preds[16b..16b+16); computes each one's global rank by counting,
// then evaluates that softmax row (one row per wave): y[rank] = sm(row).target.
// Row max of the logits is exactly 0 (diagonal term), so single-pass exp is
// numerically identical to jax's subtract-max softmax.
__global__ void k_A(const float* __restrict__ preds, const float* __restrict__ target,
                    float* __restrict__ y) {
    __shared__ __align__(16) float sp[N];
    __shared__ __align__(16) float st[N];
    __shared__ int part[16][17];
    __shared__ int rks[16];
    int tid = threadIdx.x;
    int b = blockIdx.x;
    int lane = tid & 63, wid = tid >> 6;
    for (int m = 0; m < 16; m++) {
        int idx = tid + 256 * m;
        sp[idx] = preds[idx];
        st[idx] = target[idx];
    }
    __syncthreads();
    {
        int eloc = tid & 15, slice = tid >> 4;
        int i0 = b * 16 + eloc;
        float v = sp[i0];
        int cnt = 0;
        const float4* sp4 = (const float4*)sp;
        for (int it = 0; it < 64; it++) {
            int q = slice * 64 + ((it + slice) & 63); // stagger across banks
            float4 a = sp4[q];
            int j = q * 4;
            cnt += (a.x < v) || (a.x == v && (j + 0) < i0);
            cnt += (a.y < v) || (a.y == v && (j + 1) < i0);
            cnt += (a.z < v) || (a.z == v && (j + 2) < i0);
            cnt += (a.w < v) || (a.w == v && (j + 3) < i0);
        }
        part[eloc][slice] = cnt;
    }
    __syncthreads();
    if (tid < 16) {
        int rr = 0;
        #pragma unroll
        for (int q = 0; q < 16; q++) rr += part[tid][q];
        rks[tid] = rr;
    }
    __syncthreads();
    #pragma unroll
    for (int t = 0; t < 4; t++) {
        int rr = 4 * t + wid;               // owned element 0..15
        float xv = sp[b * 16 + rr];
        float Z = 0.f, Nm = 0.f;
        #pragma unroll 4
        for (int m = 0; m < 64; m++) {
            int j = lane + 64 * m;
            float dx = xv - sp[j];
            float e = __expf(-100.0f * dx * dx);
            Z += e;
            Nm += e * st[j];
        }
        #pragma unroll
        for (int d = 32; d; d >>= 1) {
            Z += __shfl_down(Z, d);
            Nm += __shfl_down(Nm, d);
        }
        if (lane == 0) y[rks[rr]] = Nm / Z;
    }
}

// K_B: descending stable rank of y; s[r] = y*100, perm[r] = i.  256 blocks x 256.
__global__ void k_B(const float* __restrict__ y, float* __restrict__ s_out,
                    int* __restrict__ perm_out) {
    __shared__ __align__(16) float sy[N];
    __shared__ int part[16][17];
    int tid = threadIdx.x;
    int b = blockIdx.x;
    for (int m = 0; m < 16; m++) sy[tid + 256 * m] = y[tid + 256 * m];
    __syncthreads();
    int eloc = tid & 15;
    int slice = tid >> 4;
    int i = b * 16 + eloc;
    float v = sy[i];
    int cnt = 0;
    const float4* sy4 = (const float4*)sy;
    for (int it = 0; it < 64; it++) {
        int q = slice * 64 + ((it + slice) & 63);
        float4 a = sy4[q];
        int j = q * 4;
        cnt += (a.x > v) || (a.x == v && (j + 0) < i);
        cnt += (a.y > v) || (a.y == v && (j + 1) < i);
        cnt += (a.z > v) || (a.z == v && (j + 2) < i);
        cnt += (a.w > v) || (a.w == v && (j + 3) < i);
    }
    part[eloc][slice] = cnt;
    __syncthreads();
    if (tid < 16) {
        int r = 0;
        #pragma unroll
        for (int q = 0; q < 16; q++) r += part[tid][q];
        int i2 = b * 16 + tid;
        s_out[r] = sy[i2] * 100.0f;
        perm_out[r] = i2;
    }
}

// K_C: fused f64 cumsum of z[t]=(N-t)-s[t] + isotonic min-max scan.
// Block b covers rows j in [16b,16b+16); writes per-block column-max P[b][:].
__global__ void k_C(const float* __restrict__ s, float* __restrict__ P) {
    __shared__ __align__(16) float mArr[4][256];
    __shared__ float incl[4][257];
    __shared__ double cj[16];
    __shared__ double wsum[4];
    int tid = threadIdx.x;
    int b = blockIdx.x;
    int j0 = b * 16;
    int kbase = tid * 16;
    int lane = tid & 63, wid = tid >> 6;
    double loc[16];
    {
        const float4* s4 = (const float4*)s;
        double tot = 0.0;
        #pragma unroll
        for (int q = 0; q < 4; q++) {
            float4 a = s4[tid * 4 + q];
            int t0 = kbase + q * 4;
            tot += (double)(N - (t0 + 0)) - (double)a.x; loc[q * 4 + 0] = tot;
            tot += (double)(N - (t0 + 1)) - (double)a.y; loc[q * 4 + 1] = tot;
            tot += (double)(N - (t0 + 2)) - (double)a.z; loc[q * 4 + 2] = tot;
            tot += (double)(N - (t0 + 3)) - (double)a.w; loc[q * 4 + 3] = tot;
        }
        double w = tot;
        #pragma unroll
        for (int d = 1; d < 64; d <<= 1) {
            double o = __shfl_up(w, d);
            if (lane >= d) w += o;
        }
        if (lane == 63) wsum[wid] = w;
        __syncthreads();
        double base = 0.0;
        #pragma unroll
        for (int q = 0; q < 4; q++) if (q < wid) base += wsum[q];
        double excl = base + (w - tot);
        #pragma unroll
        for (int e = 0; e < 16; e++) loc[e] += excl; // loc[e] = cs[kbase+1+e]
        if (tid == b) {                              // owns cs[j0..j0+16)
            cj[0] = excl;
            #pragma unroll
            for (int m = 1; m < 16; m++) cj[m] = loc[m - 1];
        }
    }
    __syncthreads();
    float vloc[16];
    #pragma unroll
    for (int e = 0; e < 16; e++) vloc[e] = -INFINITY;
    float ls[4][16];
    for (int grp = 0; grp < 4; grp++) {
        #pragma unroll
        for (int rq = 0; rq < 4; rq++) {
            int j = j0 + grp * 4 + rq;
            double csj = cj[grp * 4 + rq];
            float run = INFINITY;
            #pragma unroll
            for (int e = 15; e >= 0; e--) {
                int k = kbase + e;
                float f = INFINITY;
                if (k >= j) f = (float)(loc[e] - csj) * __builtin_amdgcn_rcpf((float)(k - j + 1));
                run = fminf(f, run);
                ls[rq][e] = run;
            }
            mArr[rq][tid] = run;
        }
        __syncthreads();
        {
            int w = tid >> 6, l = tid & 63;
            float4 xv = ((const float4*)mArr[w])[l];
            float s3 = xv.w;
            float s2 = fminf(xv.z, s3);
            float s1 = fminf(xv.y, s2);
            float s0 = fminf(xv.x, s1);
            float t = s0;
            #pragma unroll
            for (int d = 1; d < 64; d <<= 1) {
                float o = __shfl_down(t, d);
                if (l + d < 64) t = fminf(t, o);
            }
            float after = __shfl_down(t, 1);
            if (l == 63) after = INFINITY;
            incl[w][4 * l + 0] = fminf(s0, after);
            incl[w][4 * l + 1] = fminf(s1, after);
            incl[w][4 * l + 2] = fminf(s2, after);
            incl[w][4 * l + 3] = fminf(s3, after);
            if (l == 0) incl[w][256] = INFINITY;
        }
        __syncthreads();
        #pragma unroll
        for (int rq = 0; rq < 4; rq++) {
            int j = j0 + grp * 4 + rq;
            float aft = incl[rq][tid + 1];
            #pragma unroll
            for (int e = 0; e < 16; e++) {
                int i = kbase + e;
                float sv = fminf(ls[rq][e], aft);
                if (i >= j) vloc[e] = fmaxf(vloc[e], sv);
            }
        }
        __syncthreads();
    }
    float4* P4 = (float4*)(P + (size_t)b * N);
    #pragma unroll
    for (int q = 0; q < 4; q++)
        P4[tid * 4 + q] = make_float4(vloc[4 * q + 0], vloc[4 * q + 1],
                                      vloc[4 * q + 2], vloc[4 * q + 3]);
}

// K_reduce: T[i] = max_b P[b][i]; r[perm[i]] = s[i] + T[i]. 256 blocks x 256.
__global__ void k_reduce(const float* __restrict__ P, const float* __restrict__ s,
                         const int* __restrict__ perm, float* __restrict__ r) {
    __shared__ float part[16][17];
    int tid = threadIdx.x;
    int col = tid & 15;
    int slice = tid >> 4;
    int i = blockIdx.x * 16 + col;
    float m = -INFINITY;
    #pragma unroll
    for (int q = 0; q < 16; q++) {
        int b = slice * 16 + q;
        m = fmaxf(m, P[(size_t)b * N + i]);
    }
    part[col][slice] = m;
    __syncthreads();
    if (tid < 16) {
        float T = -INFINITY;
        #pragma unroll
        for (int q = 0; q < 16; q++) T = fmaxf(T, part[tid][q]);
        int i2 = blockIdx.x * 16 + tid;
        r[perm[i2]] = s[i2] + T;
    }
}

// K_finish2: diff-sum over r in original order; emit out. 1 block x 256.
__global__ void k_finish2(const float* __restrict__ r, float* __restrict__ out) {
    __shared__ double red[4];
    int tid = threadIdx.x;
    const float4* r4 = (const float4*)r;
    float a[16];
    #pragma unroll
    for (int q = 0; q < 4; q++) {
        float4 x = r4[tid * 4 + q];
        a[q * 4 + 0] = x.x; a[q * 4 + 1] = x.y; a[q * 4 + 2] = x.z; a[q * 4 + 3] = x.w;
    }
    float extra = (tid < 255) ? r[tid * 16 + 16] : 0.0f;
    double acc = 0.0;
    #pragma unroll
    for (int e = 0; e < 16; e++) {
        int d = tid * 16 + e;
        float nxt = (e < 15) ? a[e + 1] : extra;
        if (d < N - 1) acc += fabs((double)nxt - (double)a[e]);
    }
    #pragma unroll
    for (int dd = 32; dd; dd >>= 1) acc += __shfl_down(acc, dd);
    if ((tid & 63) == 0) red[tid >> 6] = acc;
    __syncthreads();
    if (tid == 0) {
        double ds = red[0] + red[1] + red[2] + red[3];
        double xi = 1.0 - 3.0 * ds / ((double)N * (double)N - 1.0);
        out[0] = (float)(-1.0 * xi);  // loss = -WEIGHT * xi
        out[1] = (float)xi;
    }
}

extern "C" void kernel_launch(void* const* d_in, const int* in_sizes, int n_in,
                              void* d_out, int out_size, void* d_ws, size_t ws_size,
                              hipStream_t stream) {
    const float* preds  = (const float*)d_in[0];
    const float* target = (const float*)d_in[1];
    float* out = (float*)d_out;

    char* ws = (char*)d_ws;
    float* y    = (float*)(ws);            // 16 KB
    float* s    = (float*)(ws + 16384);    // 16 KB
    int*   perm = (int*)(ws + 32768);      // 16 KB
    float* r    = (float*)(ws + 49152);    // 16 KB
    float* P    = (float*)(ws + 81920);    // 4 MB

    k_A<<<256, 256, 0, stream>>>(preds, target, y);
    k_B<<<256, 256, 0, stream>>>(y, s, perm);
    k_C<<<256, 256, 0, stream>>>(s, P);
    k_reduce<<<256, 256, 0, stream>>>(P, s, perm, r);
    k_finish2<<<1, 256, 0, stream>>>(r, out);
}